// Round 5
// baseline (175.587 us; speedup 1.0000x reference)
//
#include <hip/hip_runtime.h>

// Problem constants (match reference)
#define B_    16
#define C_    80
#define H_    128
#define W_    128
#define N_    50
#define CAND_ 100
#define HW_   (H_*W_)
#define ONE_V_ 0.60653065971263342f   // exp(-0.5)
#define TWO_V_ 0.36787944117144233f   // exp(-1.0)

#define FOCAL_ITERS   16
#define FOCAL_BLOCKS  ((B_*C_*HW_) / 4 / 256 / FOCAL_ITERS)   // 1280
#define TK_BLOCKS     B_                                      // 16 (one per batch)
#define HEAT_BLOCKS   B_                                      // 16
#define TOTAL_BLOCKS  (TK_BLOCKS + HEAT_BLOCKS + FOCAL_BLOCKS)

// ws float layout (all partials written unconditionally every call):
//   [0,1280)        focal per-block partials
//   [1280,1296)     target offset-sum per-batch
//   [1296,1312)     target size-sum per-batch
//   [1312,1328)     target count per-batch (as float)
//   [1328,1344)     heat correction per-batch
#define WS_TOFF 1280
#define WS_TSIZ (1280+16)
#define WS_TCNT (1280+32)
#define WS_HEAT (1280+48)

// smem float-offset layout (target blocks); heat reuses [0,1024) as hash
#define SM_SVALS 0        // 4096 floats: window values
#define SM_HIST  4096     // 256 ints: histogram -> inclusive prefix
#define SM_LVAL  4352     // 512 floats: threshold-bucket member values
#define SM_LIDX  4864     // 512 ints: member flat indices
#define SM_CTRL  5376     // 4 ints: Bstar, R, mcount
#define SM_SBUF  5380     // 4 floats: block_reduce scratch
#define SM_TOTAL 5384

__device__ __forceinline__ float block_reduce(float v, float* sbuf) {
    __syncthreads();                       // protect sbuf reuse across calls
    #pragma unroll
    for (int o = 32; o > 0; o >>= 1) v += __shfl_down(v, o, 64);
    int lane = threadIdx.x & 63;
    int wid  = threadIdx.x >> 6;
    if (lane == 0) sbuf[wid] = v;
    __syncthreads();
    float r = 0.0f;
    if (wid == 0) {
        if (lane < 4) r = sbuf[lane];
        #pragma unroll
        for (int o = 2; o > 0; o >>= 1) r += __shfl_down(r, o, 64);
    }
    return r;  // valid on thread 0
}

__device__ __forceinline__ void hash_insert(int* hkey, int* hval, int key, float val) {
    int slot = key & 511;
    while (true) {
        int old = atomicCAS(&hkey[slot], -1, key);
        if (old == -1 || old == key) {
            atomicMax(&hval[slot], __float_as_int(val));  // positive floats: int cmp == float cmp
            break;
        }
        slot = (slot + 1) & 511;   // 512 slots >= 450 entries: always terminates
    }
}

// One fused kernel. Block order: target (16) + heat (16) FIRST so their
// latency hides under the focal bandwidth phase (R4's tail problem), then
// 1280 focal blocks. No atomics to global, all partials in private ws slots.
__global__ __launch_bounds__(256) void main_kernel(
        const float* __restrict__ cls_pred,
        const float* __restrict__ offset_pred,
        const float* __restrict__ size_pred,
        const float* __restrict__ gt_box,
        const int* __restrict__ gt_class,
        float* __restrict__ ws) {
    __shared__ float smem[SM_TOTAL];
    int bid = blockIdx.x;
    int tid = threadIdx.x;

    if (bid >= TK_BLOCKS + HEAT_BLOCKS) {
        // ---- focal base: gt==0 term p^2*log(1-p) for every cell ----
        int fb = bid - (TK_BLOCKS + HEAT_BLOCKS);
        float* sbuf = smem + SM_SBUF;
        const float4* cp = (const float4*)cls_pred;
        size_t base = (size_t)fb * 256 * FOCAL_ITERS + tid;
        float s = 0.0f;
        #pragma unroll
        for (int it = 0; it < FOCAL_ITERS; it++) {
            float4 v = cp[base + (size_t)it * 256];
            float p;
            p = fminf(fmaxf(v.x, 1e-4f), 0.9999f); s += p*p*__logf(1.0f - p);
            p = fminf(fmaxf(v.y, 1e-4f), 0.9999f); s += p*p*__logf(1.0f - p);
            p = fminf(fmaxf(v.z, 1e-4f), 0.9999f); s += p*p*__logf(1.0f - p);
            p = fminf(fmaxf(v.w, 1e-4f), 0.9999f); s += p*p*__logf(1.0f - p);
        }
        float r = block_reduce(s, sbuf);
        if (tid == 0) ws[fb] = r;

    } else if (bid < TK_BLOCKS) {
        // ---- target: CAND smallest cls_pred in window, O(M) histogram select ----
        int b = bid;
        float* svals = smem + SM_SVALS;
        int*   hist  = (int*)(smem + SM_HIST);
        float* lval  = smem + SM_LVAL;
        int*   lidx  = (int*)(smem + SM_LIDX);
        int*   ctrl  = (int*)(smem + SM_CTRL);
        float* sbuf  = smem + SM_SBUF;

        int last = -1;
        #pragma unroll
        for (int n = 0; n < N_; n++)
            if (gt_class[b*N_ + n] != -1) last = n;
        bool anyv = (last >= 0);
        int lastc = anyv ? last : 0;
        const float* bx = gt_box + ((size_t)b*N_ + lastc)*4;
        float wv = bx[2] - bx[0];
        float hv = bx[3] - bx[1];
        int gc = gt_class[b*N_ + lastc];
        int ch = gc < 0 ? 0 : gc;
        int cx = (int)floorf(floorf(wv*0.5f)*0.25f);
        int cy = (int)floorf(floorf(hv*0.5f)*0.25f);
        int w4 = (int)floorf(wv*0.25f);
        int h4 = (int)floorf(hv*0.25f);
        // Python // is floor division: arithmetic >>1 matches for all signs
        int left   = max((cx - (w4 >> 1)) >> 1, 0);
        int right  = min((cx + (w4 >> 1)) >> 1, H_/2);
        int top    = max((cy - (h4 >> 1)) >> 1, 0);
        int bottom = min((cy + (h4 >> 1)) >> 1, W_/2);
        int Mw = right - left, Mh = bottom - top;
        int M = (anyv && Mw > 0 && Mh > 0) ? Mw * Mh : 0;

        float offsum = 0.0f, sizsum = 0.0f, csum = 0.0f;
        if (M > 0) {
            hist[tid] = 0;
            if (tid == 0) { ctrl[0] = 256; ctrl[1] = 0; ctrl[2] = 0; }
            __syncthreads();
            // stage window + histogram (values uniform [0,1): bucket = floor(v*256))
            const float* cp = cls_pred + ((size_t)b*C_ + ch)*HW_;
            for (int t = tid; t < M; t += 256) {
                int i = left + t / Mh;
                int j = top  + t % Mh;
                float v = cp[i*W_ + j];
                svals[t] = v;
                atomicAdd(&hist[min((int)(v*256.0f), 255)], 1);
            }
            __syncthreads();
            // inclusive prefix sum over 256 bins (Hillis-Steele, in place)
            #pragma unroll
            for (int off = 1; off < 256; off <<= 1) {
                int vv = (tid >= off) ? hist[tid - off] : 0;
                __syncthreads();
                hist[tid] += vv;
                __syncthreads();
            }
            // threshold bin Bstar + remainder R (bucket monotone in value)
            int cum = hist[tid];
            int cumBefore = (tid == 0) ? 0 : hist[tid - 1];
            if (cum >= CAND_ && cumBefore < CAND_) { ctrl[0] = tid; ctrl[1] = CAND_ - cumBefore; }
            __syncthreads();
            int Bstar = ctrl[0], R = ctrl[1];   // Bstar=256 sentinel: M<100, all selected
            // compact Bstar members (typically M/256 ~ 5-30)
            for (int t = tid; t < M; t += 256) {
                float v = svals[t];
                if (min((int)(v*256.0f), 255) == Bstar) {
                    int pos = atomicAdd(&ctrl[2], 1);
                    if (pos < 512) { lval[pos] = v; lidx[pos] = t; }
                }
            }
            __syncthreads();
            int mcount = ctrl[2];
            float cxf = wv * 0.125f, cyf = hv * 0.125f;   // wv/2/4 exact in fp32
            float off0 = cxf - floorf(cxf);
            float off1 = cyf - floorf(cyf);
            for (int t = tid; t < M; t += 256) {
                float v = svals[t];
                int bkt = min((int)(v*256.0f), 255);
                bool selected = bkt < Bstar;
                if (bkt == Bstar) {
                    // exact (value, index)-lex rank within the bucket == top_k tie-break
                    int r = 0;
                    if (mcount <= 512) {
                        for (int q = 0; q < mcount; q++) {       // uniform q -> LDS broadcast
                            float u = lval[q]; int k = lidx[q];
                            r += (u < v) || (u == v && k < t);
                        }
                    } else {                                     // pathological overflow fallback
                        for (int k = 0; k < M; k++) {
                            float u = svals[k];
                            r += (min((int)(u*256.0f),255) == Bstar) &&
                                 ((u < v) || (u == v && k < t));
                        }
                    }
                    selected = r < R;
                }
                if (selected) {
                    int i = left + t / Mh;
                    int j = top  + t % Mh;
                    const float* op = offset_pred + (size_t)b*2*HW_ + i*W_ + j;
                    const float* sp = size_pred   + (size_t)b*2*HW_ + i*W_ + j;
                    offsum += fabsf(op[0] - off0) + fabsf(op[HW_] - off1);
                    sizsum += fabsf(sp[0] - wv)   + fabsf(sp[HW_] - hv);
                    csum   += 1.0f;
                }
            }
        }
        float ro = block_reduce(offsum, sbuf);
        float rs = block_reduce(sizsum, sbuf);
        float rc = block_reduce(csum,   sbuf);
        if (tid == 0) {
            ws[WS_TOFF + b] = ro;
            ws[WS_TSIZ + b] = rs;
            ws[WS_TCNT + b] = rc;
        }

    } else {
        // ---- heat: sparse focal correction at gt>0 cells via LDS hash (O(E)) ----
        int b = bid - TK_BLOCKS;
        int*   hkey = (int*)(smem + 0);     // 512 slots
        int*   hval = (int*)(smem + 512);   // float bits, init 0 = 0.0f
        float* sbuf = smem + SM_SBUF;
        for (int s = tid; s < 512; s += 256) { hkey[s] = -1; hval[s] = 0; }
        __syncthreads();
        if (tid < N_) {
            int n = tid;
            int gc = gt_class[b*N_ + n];
            if (gc != -1) {
                int ch = gc < 0 ? 0 : gc;
                const float* bx = gt_box + ((size_t)b*N_ + n)*4;
                float wv = bx[2] - bx[0];
                float hv = bx[3] - bx[1];
                int cx = (int)floorf(floorf(wv*0.5f)*0.25f);
                int cy = (int)floorf(floorf(hv*0.5f)*0.25f);
                if (cx >= 0 && cx < H_ && cy >= 0 && cy < W_)
                    hash_insert(hkey, hval, (ch*H_ + cx)*W_ + cy, 1.0f);
                bool interior = (cx >= 1) && (cy >= 1) && (cx + 1 < H_) && (cy + 1 < W_);
                if (interior) {
                    const int   dxs[8] = {-1,-1,-1, 0, 0, 1, 1, 1};
                    const int   dys[8] = {-1, 0, 1,-1, 1,-1, 0, 1};
                    const float vvs[8] = {TWO_V_,ONE_V_,TWO_V_,ONE_V_,ONE_V_,TWO_V_,ONE_V_,TWO_V_};
                    #pragma unroll
                    for (int q = 0; q < 8; q++)
                        hash_insert(hkey, hval,
                                    (ch*H_ + cx + dxs[q])*W_ + (cy + dys[q]), vvs[q]);
                }
            }
        }
        __syncthreads();
        float corr = 0.0f;
        for (int s = tid; s < 512; s += 256) {
            int k = hkey[s];
            if (k >= 0) {
                float g = __int_as_float(hval[s]);
                float praw = cls_pred[(size_t)b*C_*HW_ + k];
                float p  = fminf(fmaxf(praw, 1e-4f), 0.9999f);
                float lm = __logf(1.0f - p);
                float base = p*p*lm;
                float actual;
                if (g == 1.0f) {
                    float q1 = 1.0f - p; float q2 = q1*q1;
                    actual = q2*q2*__logf(p);
                } else {
                    float q1 = 1.0f - g; float q2 = q1*q1;
                    actual = q2*q2*p*p*lm;
                }
                corr += actual - base;
            }
        }
        float rc = block_reduce(corr, sbuf);
        if (tid == 0) ws[WS_HEAT + b] = rc;
    }
}

__global__ __launch_bounds__(256) void finalize_kernel(
        const float* __restrict__ ws, float* __restrict__ out) {
    __shared__ double dbuf[16];
    int tid = threadIdx.x;
    double cls = 0.0, off = 0.0, siz = 0.0, cnt = 0.0;
    for (int i = tid; i < FOCAL_BLOCKS; i += 256) cls += (double)ws[i];
    if (tid < B_) {
        off  = (double)ws[WS_TOFF + tid];
        siz  = (double)ws[WS_TSIZ + tid];
        cnt  = (double)ws[WS_TCNT + tid];
        cls += (double)ws[WS_HEAT + tid];
    }
    int lane = tid & 63, wid = tid >> 6;
    #pragma unroll
    for (int o = 32; o > 0; o >>= 1) {
        cls += __shfl_down(cls, o, 64);
        off += __shfl_down(off, o, 64);
        siz += __shfl_down(siz, o, 64);
        cnt += __shfl_down(cnt, o, 64);
    }
    if (lane == 0) {
        dbuf[wid*4+0] = cls; dbuf[wid*4+1] = off;
        dbuf[wid*4+2] = siz; dbuf[wid*4+3] = cnt;
    }
    __syncthreads();
    if (tid == 0) {
        cls = dbuf[0] + dbuf[4] + dbuf[8]  + dbuf[12];
        off = dbuf[1] + dbuf[5] + dbuf[9]  + dbuf[13];
        siz = dbuf[2] + dbuf[6] + dbuf[10] + dbuf[14];
        cnt = dbuf[3] + dbuf[7] + dbuf[11] + dbuf[15];
        int c = (int)(cnt + 0.5);
        double np_ = (double)(c < 1 ? 1 : c);
        out[0] = (float)(-cls / (double)(B_*H_*W_) + off/np_ + 0.1*siz/np_);
    }
}

extern "C" void kernel_launch(void* const* d_in, const int* in_sizes, int n_in,
                              void* d_out, int out_size, void* d_ws, size_t ws_size,
                              hipStream_t stream) {
    const float* cls_pred    = (const float*)d_in[0];
    const float* offset_pred = (const float*)d_in[1];
    const float* size_pred   = (const float*)d_in[2];
    const float* gt_box      = (const float*)d_in[3];
    const int*   gt_class    = (const int*)d_in[4];
    float* out = (float*)d_out;
    float* ws  = (float*)d_ws;

    main_kernel<<<dim3(TOTAL_BLOCKS), dim3(256), 0, stream>>>(
        cls_pred, offset_pred, size_pred, gt_box, gt_class, ws);
    finalize_kernel<<<dim3(1), dim3(256), 0, stream>>>(ws, out);
}

// Round 6
// 130.582 us; speedup vs baseline: 1.3446x; 1.3446x over previous
//
#include <hip/hip_runtime.h>

// Problem constants (match reference)
#define B_    16
#define C_    80
#define H_    128
#define W_    128
#define N_    50
#define CAND_ 100
#define HW_   (H_*W_)
#define ONE_V_ 0.60653065971263342f   // exp(-0.5)
#define TWO_V_ 0.36787944117144233f   // exp(-1.0)

#define FOCAL_ITERS   16
#define FOCAL_BLOCKS  ((B_*C_*HW_) / 4 / 256 / FOCAL_ITERS)   // 1280
#define TK_BLOCKS     B_                                      // 16 (one per batch)
#define HEAT_BLOCKS   B_                                      // 16
#define TOTAL_BLOCKS  (TK_BLOCKS + HEAT_BLOCKS + FOCAL_BLOCKS)

// ws float layout (all partials written unconditionally every call):
//   [0,1280)        focal per-block partials
//   [1280,1296)     target offset-sum per-batch
//   [1296,1312)     target size-sum per-batch
//   [1312,1328)     target count per-batch (as float)
//   [1328,1344)     heat correction per-batch
#define WS_TOFF 1280
#define WS_TSIZ (1280+16)
#define WS_TCNT (1280+32)
#define WS_HEAT (1280+48)

// smem float-offset layout (target blocks); heat reuses [0,2048) as hash
#define SM_SVALS 0        // 4096 floats: window values
#define SM_HIST  4096     // 256 ints: histogram -> inclusive prefix
#define SM_LVAL  4352     // 512 floats: threshold-bucket member values
#define SM_LIDX  4864     // 512 ints: member flat indices
#define SM_CTRL  5376     // 4 ints: Bstar, R, mcount
#define SM_SBUF  5380     // 4 floats: block_reduce scratch
#define SM_TOTAL 5384

__device__ __forceinline__ float block_reduce(float v, float* sbuf) {
    __syncthreads();                       // protect sbuf reuse across calls
    #pragma unroll
    for (int o = 32; o > 0; o >>= 1) v += __shfl_down(v, o, 64);
    int lane = threadIdx.x & 63;
    int wid  = threadIdx.x >> 6;
    if (lane == 0) sbuf[wid] = v;
    __syncthreads();
    float r = 0.0f;
    if (wid == 0) {
        if (lane < 4) r = sbuf[lane];
        #pragma unroll
        for (int o = 2; o > 0; o >>= 1) r += __shfl_down(r, o, 64);
    }
    return r;  // valid on thread 0
}

// R5 bug: slot = key&511 dropped the class term (16384%512==0) and cy spans
// only ~30 values -> 450 keys in ~120 slots, 50-100-probe chains, ~50us.
// R6: multiplicative mix over 1024 slots (load 0.44) -> ~1.5 probes.
__device__ __forceinline__ void hash_insert(int* hkey, int* hval, int key, float val) {
    int slot = (int)(((unsigned)key * 2654435761u) >> 22) & 1023;
    while (true) {
        int old = atomicCAS(&hkey[slot], -1, key);
        if (old == -1 || old == key) {
            atomicMax(&hval[slot], __float_as_int(val));  // positive floats: int cmp == float cmp
            break;
        }
        slot = (slot + 1) & 1023;   // 1024 slots >= 450 entries: terminates
    }
}

// One fused kernel: 16 target + 16 heat + 1280 focal blocks, all independent,
// all writing private ws slots (no global atomics, no init kernel).
__global__ __launch_bounds__(256) void main_kernel(
        const float* __restrict__ cls_pred,
        const float* __restrict__ offset_pred,
        const float* __restrict__ size_pred,
        const float* __restrict__ gt_box,
        const int* __restrict__ gt_class,
        float* __restrict__ ws) {
    __shared__ float smem[SM_TOTAL];
    int bid = blockIdx.x;
    int tid = threadIdx.x;

    if (bid >= TK_BLOCKS + HEAT_BLOCKS) {
        // ---- focal base: gt==0 term p^2*log(1-p) for every cell ----
        int fb = bid - (TK_BLOCKS + HEAT_BLOCKS);
        float* sbuf = smem + SM_SBUF;
        const float4* cp = (const float4*)cls_pred;
        size_t base = (size_t)fb * 256 * FOCAL_ITERS + tid;
        float s = 0.0f;
        #pragma unroll
        for (int it = 0; it < FOCAL_ITERS; it++) {
            float4 v = cp[base + (size_t)it * 256];
            float p;
            p = fminf(fmaxf(v.x, 1e-4f), 0.9999f); s += p*p*__logf(1.0f - p);
            p = fminf(fmaxf(v.y, 1e-4f), 0.9999f); s += p*p*__logf(1.0f - p);
            p = fminf(fmaxf(v.z, 1e-4f), 0.9999f); s += p*p*__logf(1.0f - p);
            p = fminf(fmaxf(v.w, 1e-4f), 0.9999f); s += p*p*__logf(1.0f - p);
        }
        float r = block_reduce(s, sbuf);
        if (tid == 0) ws[fb] = r;

    } else if (bid < TK_BLOCKS) {
        // ---- target: CAND smallest cls_pred in window, O(M) histogram select ----
        int b = bid;
        float* svals = smem + SM_SVALS;
        int*   hist  = (int*)(smem + SM_HIST);
        float* lval  = smem + SM_LVAL;
        int*   lidx  = (int*)(smem + SM_LIDX);
        int*   ctrl  = (int*)(smem + SM_CTRL);
        float* sbuf  = smem + SM_SBUF;

        int last = -1;
        for (int n = 0; n < N_; n++)
            if (gt_class[b*N_ + n] != -1) last = n;
        bool anyv = (last >= 0);
        int lastc = anyv ? last : 0;
        const float* bx = gt_box + ((size_t)b*N_ + lastc)*4;
        float wv = bx[2] - bx[0];
        float hv = bx[3] - bx[1];
        int gc = gt_class[b*N_ + lastc];
        int ch = gc < 0 ? 0 : gc;
        int cx = (int)floorf(floorf(wv*0.5f)*0.25f);
        int cy = (int)floorf(floorf(hv*0.5f)*0.25f);
        int w4 = (int)floorf(wv*0.25f);
        int h4 = (int)floorf(hv*0.25f);
        // Python // is floor division: arithmetic >>1 matches for all signs
        int left   = max((cx - (w4 >> 1)) >> 1, 0);
        int right  = min((cx + (w4 >> 1)) >> 1, H_/2);
        int top    = max((cy - (h4 >> 1)) >> 1, 0);
        int bottom = min((cy + (h4 >> 1)) >> 1, W_/2);
        int Mw = right - left, Mh = bottom - top;
        int M = (anyv && Mw > 0 && Mh > 0) ? Mw * Mh : 0;

        float offsum = 0.0f, sizsum = 0.0f, csum = 0.0f;
        if (M > 0) {
            hist[tid] = 0;
            if (tid == 0) { ctrl[0] = 256; ctrl[1] = 0; ctrl[2] = 0; }
            __syncthreads();
            // stage window + histogram (values uniform [0,1): bucket = floor(v*256))
            const float* cp = cls_pred + ((size_t)b*C_ + ch)*HW_;
            for (int t = tid; t < M; t += 256) {
                int i = left + t / Mh;
                int j = top  + t % Mh;
                float v = cp[i*W_ + j];
                svals[t] = v;
                atomicAdd(&hist[min((int)(v*256.0f), 255)], 1);
            }
            __syncthreads();
            // inclusive prefix sum over 256 bins (Hillis-Steele, in place)
            #pragma unroll
            for (int off = 1; off < 256; off <<= 1) {
                int vv = (tid >= off) ? hist[tid - off] : 0;
                __syncthreads();
                hist[tid] += vv;
                __syncthreads();
            }
            // threshold bin Bstar + remainder R (bucket monotone in value)
            int cum = hist[tid];
            int cumBefore = (tid == 0) ? 0 : hist[tid - 1];
            if (cum >= CAND_ && cumBefore < CAND_) { ctrl[0] = tid; ctrl[1] = CAND_ - cumBefore; }
            __syncthreads();
            int Bstar = ctrl[0], R = ctrl[1];   // Bstar=256 sentinel: M<100, all selected
            // compact Bstar members (typically M/256 ~ 5-30)
            for (int t = tid; t < M; t += 256) {
                float v = svals[t];
                if (min((int)(v*256.0f), 255) == Bstar) {
                    int pos = atomicAdd(&ctrl[2], 1);
                    if (pos < 512) { lval[pos] = v; lidx[pos] = t; }
                }
            }
            __syncthreads();
            int mcount = ctrl[2];
            float cxf = wv * 0.125f, cyf = hv * 0.125f;   // wv/2/4 exact in fp32
            float off0 = cxf - floorf(cxf);
            float off1 = cyf - floorf(cyf);
            for (int t = tid; t < M; t += 256) {
                float v = svals[t];
                int bkt = min((int)(v*256.0f), 255);
                bool selected = bkt < Bstar;
                if (bkt == Bstar) {
                    // exact (value, index)-lex rank within the bucket == top_k tie-break
                    int r = 0;
                    if (mcount <= 512) {
                        for (int q = 0; q < mcount; q++) {       // uniform q -> LDS broadcast
                            float u = lval[q]; int k = lidx[q];
                            r += (u < v) || (u == v && k < t);
                        }
                    } else {                                     // pathological overflow fallback
                        for (int k = 0; k < M; k++) {
                            float u = svals[k];
                            r += (min((int)(u*256.0f),255) == Bstar) &&
                                 ((u < v) || (u == v && k < t));
                        }
                    }
                    selected = r < R;
                }
                if (selected) {
                    int i = left + t / Mh;
                    int j = top  + t % Mh;
                    const float* op = offset_pred + (size_t)b*2*HW_ + i*W_ + j;
                    const float* sp = size_pred   + (size_t)b*2*HW_ + i*W_ + j;
                    offsum += fabsf(op[0] - off0) + fabsf(op[HW_] - off1);
                    sizsum += fabsf(sp[0] - wv)   + fabsf(sp[HW_] - hv);
                    csum   += 1.0f;
                }
            }
        }
        float ro = block_reduce(offsum, sbuf);
        float rs = block_reduce(sizsum, sbuf);
        float rc = block_reduce(csum,   sbuf);
        if (tid == 0) {
            ws[WS_TOFF + b] = ro;
            ws[WS_TSIZ + b] = rs;
            ws[WS_TCNT + b] = rc;
        }

    } else {
        // ---- heat: sparse focal correction at gt>0 cells via LDS hash (O(E)) ----
        int b = bid - TK_BLOCKS;
        int*   hkey = (int*)(smem + 0);      // 1024 slots
        int*   hval = (int*)(smem + 1024);   // float bits, init 0 = 0.0f
        float* sbuf = smem + SM_SBUF;
        for (int s = tid; s < 1024; s += 256) { hkey[s] = -1; hval[s] = 0; }
        __syncthreads();
        // parallel insert: 450 (keypoint, entry) pairs over 256 threads
        for (int e = tid; e < 9*N_; e += 256) {
            int n = e / 9, q = e % 9;
            int gc = gt_class[b*N_ + n];
            if (gc == -1) continue;
            int ch = gc < 0 ? 0 : gc;
            const float* bx = gt_box + ((size_t)b*N_ + n)*4;
            float wv = bx[2] - bx[0];
            float hv = bx[3] - bx[1];
            int cx = (int)floorf(floorf(wv*0.5f)*0.25f);
            int cy = (int)floorf(floorf(hv*0.5f)*0.25f);
            if (q == 0) {
                if (cx >= 0 && cx < H_ && cy >= 0 && cy < W_)
                    hash_insert(hkey, hval, (ch*H_ + cx)*W_ + cy, 1.0f);
            } else {
                bool interior = (cx >= 1) && (cy >= 1) && (cx + 1 < H_) && (cy + 1 < W_);
                if (interior) {
                    int idx = (q - 1) < 4 ? (q - 1) : q;     // 0..8 skipping center 4
                    int dx = idx / 3 - 1;
                    int dy = idx % 3 - 1;
                    float vv = (dx == 0 || dy == 0) ? ONE_V_ : TWO_V_;  // order-free: max dedup
                    hash_insert(hkey, hval, (ch*H_ + cx + dx)*W_ + (cy + dy), vv);
                }
            }
        }
        __syncthreads();
        float corr = 0.0f;
        for (int s = tid; s < 1024; s += 256) {
            int k = hkey[s];
            if (k >= 0) {
                float g = __int_as_float(hval[s]);
                float praw = cls_pred[(size_t)b*C_*HW_ + k];
                float p  = fminf(fmaxf(praw, 1e-4f), 0.9999f);
                float lm = __logf(1.0f - p);
                float base = p*p*lm;
                float actual;
                if (g == 1.0f) {
                    float q1 = 1.0f - p; float q2 = q1*q1;
                    actual = q2*q2*__logf(p);
                } else {
                    float q1 = 1.0f - g; float q2 = q1*q1;
                    actual = q2*q2*p*p*lm;
                }
                corr += actual - base;
            }
        }
        float rc = block_reduce(corr, sbuf);
        if (tid == 0) ws[WS_HEAT + b] = rc;
    }
}

__global__ __launch_bounds__(256) void finalize_kernel(
        const float* __restrict__ ws, float* __restrict__ out) {
    __shared__ double dbuf[16];
    int tid = threadIdx.x;
    double cls = 0.0, off = 0.0, siz = 0.0, cnt = 0.0;
    for (int i = tid; i < FOCAL_BLOCKS; i += 256) cls += (double)ws[i];
    if (tid < B_) {
        off  = (double)ws[WS_TOFF + tid];
        siz  = (double)ws[WS_TSIZ + tid];
        cnt  = (double)ws[WS_TCNT + tid];
        cls += (double)ws[WS_HEAT + tid];
    }
    int lane = tid & 63, wid = tid >> 6;
    #pragma unroll
    for (int o = 32; o > 0; o >>= 1) {
        cls += __shfl_down(cls, o, 64);
        off += __shfl_down(off, o, 64);
        siz += __shfl_down(siz, o, 64);
        cnt += __shfl_down(cnt, o, 64);
    }
    if (lane == 0) {
        dbuf[wid*4+0] = cls; dbuf[wid*4+1] = off;
        dbuf[wid*4+2] = siz; dbuf[wid*4+3] = cnt;
    }
    __syncthreads();
    if (tid == 0) {
        cls = dbuf[0] + dbuf[4] + dbuf[8]  + dbuf[12];
        off = dbuf[1] + dbuf[5] + dbuf[9]  + dbuf[13];
        siz = dbuf[2] + dbuf[6] + dbuf[10] + dbuf[14];
        cnt = dbuf[3] + dbuf[7] + dbuf[11] + dbuf[15];
        int c = (int)(cnt + 0.5);
        double np_ = (double)(c < 1 ? 1 : c);
        out[0] = (float)(-cls / (double)(B_*H_*W_) + off/np_ + 0.1*siz/np_);
    }
}

extern "C" void kernel_launch(void* const* d_in, const int* in_sizes, int n_in,
                              void* d_out, int out_size, void* d_ws, size_t ws_size,
                              hipStream_t stream) {
    const float* cls_pred    = (const float*)d_in[0];
    const float* offset_pred = (const float*)d_in[1];
    const float* size_pred   = (const float*)d_in[2];
    const float* gt_box      = (const float*)d_in[3];
    const int*   gt_class    = (const int*)d_in[4];
    float* out = (float*)d_out;
    float* ws  = (float*)d_ws;

    main_kernel<<<dim3(TOTAL_BLOCKS), dim3(256), 0, stream>>>(
        cls_pred, offset_pred, size_pred, gt_box, gt_class, ws);
    finalize_kernel<<<dim3(1), dim3(256), 0, stream>>>(ws, out);
}

// Round 7
// 127.216 us; speedup vs baseline: 1.3802x; 1.0265x over previous
//
#include <hip/hip_runtime.h>

// Problem constants (match reference)
#define B_    16
#define C_    80
#define H_    128
#define W_    128
#define N_    50
#define CAND_ 100
#define HW_   (H_*W_)
#define ONE_V_ 0.60653065971263342f   // exp(-0.5)
#define TWO_V_ 0.36787944117144233f   // exp(-1.0)

#define TK_BLOCKS     B_          // 16 (one per batch)
#define HEAT_BLOCKS   B_          // 16
#define FOCAL_BLOCKS  1248        // 32+1248 = 1280 = exactly 5 blocks/CU (R6 ran 5.125 -> +1 block-round tail)
#define TOTAL_BLOCKS  (TK_BLOCKS + HEAT_BLOCKS + FOCAL_BLOCKS)
#define F4_TOTAL      (B_*C_*HW_/4)            // 5,242,880 float4
#define F_THREADS     (FOCAL_BLOCKS*256)       // 319,488
// per-thread: 16 guaranteed strided float4s + 1 conditional tail
// 16*F_THREADS = 5,111,808; remainder 131,072 threads do one more.

// ws float layout (every slot written unconditionally every call -> no init
// needed under the harness's 0xAA ws re-poison):
//   [0,1248)       focal per-block partials
//   [1248,1264)    target offset-sum per-batch
//   [1264,1280)    target size-sum per-batch
//   [1280,1296)    target count per-batch (as float)
//   [1296,1312)    heat correction per-batch
#define WS_TOFF 1248
#define WS_TSIZ (1248+16)
#define WS_TCNT (1248+32)
#define WS_HEAT (1248+48)

// smem float-offset layout (target blocks); heat reuses [0,2048) as hash
#define SM_SVALS 0        // 4096 floats: window values
#define SM_HIST  4096     // 256 ints: histogram -> inclusive prefix
#define SM_LVAL  4352     // 512 floats: threshold-bucket member values
#define SM_LIDX  4864     // 512 ints: member flat indices
#define SM_CTRL  5376     // 4 ints: Bstar, R, mcount
#define SM_SBUF  5380     // 4 floats: block_reduce scratch
#define SM_TOTAL 5384

__device__ __forceinline__ float block_reduce(float v, float* sbuf) {
    __syncthreads();                       // protect sbuf reuse across calls
    #pragma unroll
    for (int o = 32; o > 0; o >>= 1) v += __shfl_down(v, o, 64);
    int lane = threadIdx.x & 63;
    int wid  = threadIdx.x >> 6;
    if (lane == 0) sbuf[wid] = v;
    __syncthreads();
    float r = 0.0f;
    if (wid == 0) {
        if (lane < 4) r = sbuf[lane];
        #pragma unroll
        for (int o = 2; o > 0; o >>= 1) r += __shfl_down(r, o, 64);
    }
    return r;  // valid on thread 0
}

// Multiplicative-mix hash over 1024 slots (load 0.44 -> ~1.5 probes).
// (R5's key&511 dropped the class term and clustered 450 keys into ~120 slots.)
__device__ __forceinline__ void hash_insert(int* hkey, int* hval, int key, float val) {
    int slot = (int)(((unsigned)key * 2654435761u) >> 22) & 1023;
    while (true) {
        int old = atomicCAS(&hkey[slot], -1, key);
        if (old == -1 || old == key) {
            atomicMax(&hval[slot], __float_as_int(val));  // positive floats: int cmp == float cmp
            break;
        }
        slot = (slot + 1) & 1023;
    }
}

// One fused kernel: 16 target + 16 heat + 1248 focal blocks, all independent,
// all writing private ws slots (no global atomics, no init kernel).
__global__ __launch_bounds__(256) void main_kernel(
        const float* __restrict__ cls_pred,
        const float* __restrict__ offset_pred,
        const float* __restrict__ size_pred,
        const float* __restrict__ gt_box,
        const int* __restrict__ gt_class,
        float* __restrict__ ws) {
    __shared__ float smem[SM_TOTAL];
    int bid = blockIdx.x;
    int tid = threadIdx.x;

    if (bid >= TK_BLOCKS + HEAT_BLOCKS) {
        // ---- focal base: gt==0 term p^2*log(1-p) for every cell ----
        int fb = bid - (TK_BLOCKS + HEAT_BLOCKS);
        float* sbuf = smem + SM_SBUF;
        const float4* cp = (const float4*)cls_pred;
        int t = fb * 256 + tid;              // linear thread id in [0, F_THREADS)
        float s = 0.0f;
        #pragma unroll
        for (int it = 0; it < 16; it++) {
            float4 v = cp[(size_t)t + (size_t)it * F_THREADS];
            float p;
            p = fminf(fmaxf(v.x, 1e-4f), 0.9999f); s += p*p*__logf(1.0f - p);
            p = fminf(fmaxf(v.y, 1e-4f), 0.9999f); s += p*p*__logf(1.0f - p);
            p = fminf(fmaxf(v.z, 1e-4f), 0.9999f); s += p*p*__logf(1.0f - p);
            p = fminf(fmaxf(v.w, 1e-4f), 0.9999f); s += p*p*__logf(1.0f - p);
        }
        if (t < F4_TOTAL - 16 * F_THREADS) {  // tail: first 131072 threads
            float4 v = cp[(size_t)t + (size_t)16 * F_THREADS];
            float p;
            p = fminf(fmaxf(v.x, 1e-4f), 0.9999f); s += p*p*__logf(1.0f - p);
            p = fminf(fmaxf(v.y, 1e-4f), 0.9999f); s += p*p*__logf(1.0f - p);
            p = fminf(fmaxf(v.z, 1e-4f), 0.9999f); s += p*p*__logf(1.0f - p);
            p = fminf(fmaxf(v.w, 1e-4f), 0.9999f); s += p*p*__logf(1.0f - p);
        }
        float r = block_reduce(s, sbuf);
        if (tid == 0) ws[fb] = r;

    } else if (bid < TK_BLOCKS) {
        // ---- target: CAND smallest cls_pred in window, O(M) histogram select ----
        int b = bid;
        float* svals = smem + SM_SVALS;
        int*   hist  = (int*)(smem + SM_HIST);
        float* lval  = smem + SM_LVAL;
        int*   lidx  = (int*)(smem + SM_LIDX);
        int*   ctrl  = (int*)(smem + SM_CTRL);
        float* sbuf  = smem + SM_SBUF;

        int last = -1;
        for (int n = 0; n < N_; n++)
            if (gt_class[b*N_ + n] != -1) last = n;
        bool anyv = (last >= 0);
        int lastc = anyv ? last : 0;
        const float* bx = gt_box + ((size_t)b*N_ + lastc)*4;
        float wv = bx[2] - bx[0];
        float hv = bx[3] - bx[1];
        int gc = gt_class[b*N_ + lastc];
        int ch = gc < 0 ? 0 : gc;
        int cx = (int)floorf(floorf(wv*0.5f)*0.25f);
        int cy = (int)floorf(floorf(hv*0.5f)*0.25f);
        int w4 = (int)floorf(wv*0.25f);
        int h4 = (int)floorf(hv*0.25f);
        // Python // is floor division: arithmetic >>1 matches for all signs
        int left   = max((cx - (w4 >> 1)) >> 1, 0);
        int right  = min((cx + (w4 >> 1)) >> 1, H_/2);
        int top    = max((cy - (h4 >> 1)) >> 1, 0);
        int bottom = min((cy + (h4 >> 1)) >> 1, W_/2);
        int Mw = right - left, Mh = bottom - top;
        int M = (anyv && Mw > 0 && Mh > 0) ? Mw * Mh : 0;

        float offsum = 0.0f, sizsum = 0.0f, csum = 0.0f;
        if (M > 0) {
            hist[tid] = 0;
            if (tid == 0) { ctrl[0] = 256; ctrl[1] = 0; ctrl[2] = 0; }
            __syncthreads();
            // stage window + histogram (values uniform [0,1): bucket = floor(v*256))
            const float* cp = cls_pred + ((size_t)b*C_ + ch)*HW_;
            for (int t = tid; t < M; t += 256) {
                int i = left + t / Mh;
                int j = top  + t % Mh;
                float v = cp[i*W_ + j];
                svals[t] = v;
                atomicAdd(&hist[min((int)(v*256.0f), 255)], 1);
            }
            __syncthreads();
            // inclusive prefix sum over 256 bins (Hillis-Steele, in place)
            #pragma unroll
            for (int off = 1; off < 256; off <<= 1) {
                int vv = (tid >= off) ? hist[tid - off] : 0;
                __syncthreads();
                hist[tid] += vv;
                __syncthreads();
            }
            // threshold bin Bstar + remainder R (bucket monotone in value)
            int cum = hist[tid];
            int cumBefore = (tid == 0) ? 0 : hist[tid - 1];
            if (cum >= CAND_ && cumBefore < CAND_) { ctrl[0] = tid; ctrl[1] = CAND_ - cumBefore; }
            __syncthreads();
            int Bstar = ctrl[0], R = ctrl[1];   // Bstar=256 sentinel: M<100, all selected
            // compact Bstar members (typically M/256 ~ 5-15)
            for (int t = tid; t < M; t += 256) {
                float v = svals[t];
                if (min((int)(v*256.0f), 255) == Bstar) {
                    int pos = atomicAdd(&ctrl[2], 1);
                    if (pos < 512) { lval[pos] = v; lidx[pos] = t; }
                }
            }
            __syncthreads();
            int mcount = ctrl[2];
            float cxf = wv * 0.125f, cyf = hv * 0.125f;   // wv/2/4 exact in fp32
            float off0 = cxf - floorf(cxf);
            float off1 = cyf - floorf(cyf);
            for (int t = tid; t < M; t += 256) {
                float v = svals[t];
                int bkt = min((int)(v*256.0f), 255);
                bool selected = bkt < Bstar;
                if (bkt == Bstar) {
                    // exact (value, index)-lex rank within the bucket == top_k tie-break
                    int r = 0;
                    if (mcount <= 512) {
                        for (int q = 0; q < mcount; q++) {       // uniform q -> LDS broadcast
                            float u = lval[q]; int k = lidx[q];
                            r += (u < v) || (u == v && k < t);
                        }
                    } else {                                     // pathological overflow fallback
                        for (int k = 0; k < M; k++) {
                            float u = svals[k];
                            r += (min((int)(u*256.0f),255) == Bstar) &&
                                 ((u < v) || (u == v && k < t));
                        }
                    }
                    selected = r < R;
                }
                if (selected) {
                    int i = left + t / Mh;
                    int j = top  + t % Mh;
                    const float* op = offset_pred + (size_t)b*2*HW_ + i*W_ + j;
                    const float* sp = size_pred   + (size_t)b*2*HW_ + i*W_ + j;
                    offsum += fabsf(op[0] - off0) + fabsf(op[HW_] - off1);
                    sizsum += fabsf(sp[0] - wv)   + fabsf(sp[HW_] - hv);
                    csum   += 1.0f;
                }
            }
        }
        float ro = block_reduce(offsum, sbuf);
        float rs = block_reduce(sizsum, sbuf);
        float rc = block_reduce(csum,   sbuf);
        if (tid == 0) {
            ws[WS_TOFF + b] = ro;
            ws[WS_TSIZ + b] = rs;
            ws[WS_TCNT + b] = rc;
        }

    } else {
        // ---- heat: sparse focal correction at gt>0 cells via LDS hash (O(E)) ----
        int b = bid - TK_BLOCKS;
        int*   hkey = (int*)(smem + 0);      // 1024 slots
        int*   hval = (int*)(smem + 1024);   // float bits, init 0 = 0.0f
        float* sbuf = smem + SM_SBUF;
        for (int s = tid; s < 1024; s += 256) { hkey[s] = -1; hval[s] = 0; }
        __syncthreads();
        // parallel insert: 450 (keypoint, entry) pairs over 256 threads
        for (int e = tid; e < 9*N_; e += 256) {
            int n = e / 9, q = e % 9;
            int gc = gt_class[b*N_ + n];
            if (gc == -1) continue;
            int ch = gc < 0 ? 0 : gc;
            const float* bx = gt_box + ((size_t)b*N_ + n)*4;
            float wv = bx[2] - bx[0];
            float hv = bx[3] - bx[1];
            int cx = (int)floorf(floorf(wv*0.5f)*0.25f);
            int cy = (int)floorf(floorf(hv*0.5f)*0.25f);
            if (q == 0) {
                if (cx >= 0 && cx < H_ && cy >= 0 && cy < W_)
                    hash_insert(hkey, hval, (ch*H_ + cx)*W_ + cy, 1.0f);
            } else {
                bool interior = (cx >= 1) && (cy >= 1) && (cx + 1 < H_) && (cy + 1 < W_);
                if (interior) {
                    int idx = (q - 1) < 4 ? (q - 1) : q;     // 0..8 skipping center 4
                    int dx = idx / 3 - 1;
                    int dy = idx % 3 - 1;
                    float vv = (dx == 0 || dy == 0) ? ONE_V_ : TWO_V_;  // order-free: max dedup
                    hash_insert(hkey, hval, (ch*H_ + cx + dx)*W_ + (cy + dy), vv);
                }
            }
        }
        __syncthreads();
        float corr = 0.0f;
        for (int s = tid; s < 1024; s += 256) {
            int k = hkey[s];
            if (k >= 0) {
                float g = __int_as_float(hval[s]);
                float praw = cls_pred[(size_t)b*C_*HW_ + k];
                float p  = fminf(fmaxf(praw, 1e-4f), 0.9999f);
                float lm = __logf(1.0f - p);
                float base = p*p*lm;
                float actual;
                if (g == 1.0f) {
                    float q1 = 1.0f - p; float q2 = q1*q1;
                    actual = q2*q2*__logf(p);
                } else {
                    float q1 = 1.0f - g; float q2 = q1*q1;
                    actual = q2*q2*p*p*lm;
                }
                corr += actual - base;
            }
        }
        float rc = block_reduce(corr, sbuf);
        if (tid == 0) ws[WS_HEAT + b] = rc;
    }
}

__global__ __launch_bounds__(256) void finalize_kernel(
        const float* __restrict__ ws, float* __restrict__ out) {
    __shared__ double dbuf[16];
    int tid = threadIdx.x;
    double cls = 0.0, off = 0.0, siz = 0.0, cnt = 0.0;
    // focal partials as float4 (1248 = 312 float4s, 2 rounds)
    const float4* p4 = (const float4*)ws;
    if (tid < 312) { float4 v = p4[tid]; cls += (double)v.x + v.y + v.z + v.w; }
    int t2 = tid + 256;
    if (t2 < 312) { float4 v = p4[t2]; cls += (double)v.x + v.y + v.z + v.w; }
    if (tid < B_) {
        off  = (double)ws[WS_TOFF + tid];
        siz  = (double)ws[WS_TSIZ + tid];
        cnt  = (double)ws[WS_TCNT + tid];
        cls += (double)ws[WS_HEAT + tid];
    }
    int lane = tid & 63, wid = tid >> 6;
    #pragma unroll
    for (int o = 32; o > 0; o >>= 1) {
        cls += __shfl_down(cls, o, 64);
        off += __shfl_down(off, o, 64);
        siz += __shfl_down(siz, o, 64);
        cnt += __shfl_down(cnt, o, 64);
    }
    if (lane == 0) {
        dbuf[wid*4+0] = cls; dbuf[wid*4+1] = off;
        dbuf[wid*4+2] = siz; dbuf[wid*4+3] = cnt;
    }
    __syncthreads();
    if (tid == 0) {
        cls = dbuf[0] + dbuf[4] + dbuf[8]  + dbuf[12];
        off = dbuf[1] + dbuf[5] + dbuf[9]  + dbuf[13];
        siz = dbuf[2] + dbuf[6] + dbuf[10] + dbuf[14];
        cnt = dbuf[3] + dbuf[7] + dbuf[11] + dbuf[15];
        int c = (int)(cnt + 0.5);
        double np_ = (double)(c < 1 ? 1 : c);
        out[0] = (float)(-cls / (double)(B_*H_*W_) + off/np_ + 0.1*siz/np_);
    }
}

extern "C" void kernel_launch(void* const* d_in, const int* in_sizes, int n_in,
                              void* d_out, int out_size, void* d_ws, size_t ws_size,
                              hipStream_t stream) {
    const float* cls_pred    = (const float*)d_in[0];
    const float* offset_pred = (const float*)d_in[1];
    const float* size_pred   = (const float*)d_in[2];
    const float* gt_box      = (const float*)d_in[3];
    const int*   gt_class    = (const int*)d_in[4];
    float* out = (float*)d_out;
    float* ws  = (float*)d_ws;

    main_kernel<<<dim3(TOTAL_BLOCKS), dim3(256), 0, stream>>>(
        cls_pred, offset_pred, size_pred, gt_box, gt_class, ws);
    finalize_kernel<<<dim3(1), dim3(256), 0, stream>>>(ws, out);
}